// Round 2
// baseline (156.008 us; speedup 1.0000x reference)
//
#include <hip/hip_runtime.h>

typedef float f32x4 __attribute__((ext_vector_type(4)));

#define NSEAS 3
#define NRES  2
#define NCOMP 5
#define KNB   8
#define TWO_PI_F 6.28318530717958647692f
#define SPB 49           // stations per signals-block (49*2041 >= 100000)
#define BSIG 256         // signals block size

// ---------------------------------------------------------------------------
// ws layout (floats): [0, N*12)            params
//                     [N*12, N*12+5T)      sinT[comp][t]
//                     [N*12+5T, N*12+10T)  cosT[comp][t]
// ---------------------------------------------------------------------------

// Tiny kernel: 2*pi*f_c*t sin/cos tables, 5 components x T.
__global__ void build_tables_kernel(
    const float* __restrict__ time_vector,
    const float* __restrict__ periods,
    const float* __restrict__ res_periods,
    float* __restrict__ sinT,
    float* __restrict__ cosT,
    int T)
{
    int t = blockIdx.x * blockDim.x + threadIdx.x;
    if (t >= T) return;
    float tt = time_vector[t];
    #pragma unroll
    for (int c = 0; c < NCOMP; ++c) {
        float f = (c < NSEAS) ? (1.0f / periods[c])
                              : (1.0f / res_periods[c - NSEAS]);
        float s, co;
        sincosf(TWO_PI_F * f * tt, &s, &co);
        sinT[c * T + t] = s;
        cosT[c * T + t] = co;
    }
}

// Kernel A: spatial smoothing -> 12 coefficients per station.
// params[st*12 + 0] = offset, +1 = trend,
// +2+2i = A_i*cos(phi_i) (sin-basis coeff), +3+2i = A_i*sin(phi_i) (cos-basis)
__global__ void smooth_params_kernel(
    const float* __restrict__ constant_offset,
    const float* __restrict__ linear_trend,
    const float* __restrict__ seas_amp,
    const float* __restrict__ seas_phase,
    const float* __restrict__ res_amp,
    const float* __restrict__ res_phase,
    const int*   __restrict__ nb_idx,
    const float* __restrict__ nb_w,
    float* __restrict__ params,
    int N)
{
    int st = blockIdx.x * blockDim.x + threadIdx.x;
    if (st >= N) return;

    const float S = 0.12f, OMS = 1.0f - 0.12f;

    // 32B-per-thread vector loads of neighbor idx/weights.
    const int4*  ip = reinterpret_cast<const int4*>(nb_idx + st * KNB);
    const f32x4* wp = reinterpret_cast<const f32x4*>(nb_w + st * KNB);
    int4  i0 = ip[0], i1 = ip[1];
    f32x4 w0 = wp[0], w1 = wp[1];
    int   idx[KNB] = {i0.x, i0.y, i0.z, i0.w, i1.x, i1.y, i1.z, i1.w};
    float w[KNB]   = {w0.x, w0.y, w0.z, w0.w, w1.x, w1.y, w1.z, w1.w};

    float accA[NSEAS]  = {0.f, 0.f, 0.f};
    float accRe[NSEAS] = {0.f, 0.f, 0.f};
    float accIm[NSEAS] = {0.f, 0.f, 0.f};

    #pragma unroll
    for (int k = 0; k < KNB; ++k) {
        int nb = idx[k];
        #pragma unroll
        for (int i = 0; i < NSEAS; ++i) {
            float a = seas_amp[nb * NSEAS + i];
            float p = seas_phase[nb * NSEAS + i];
            float sp, cp;
            sincosf(p, &sp, &cp);
            accA[i]  = fmaf(w[k], a,  accA[i]);
            accRe[i] = fmaf(w[k], cp, accRe[i]);
            accIm[i] = fmaf(w[k], sp, accIm[i]);
        }
    }

    float outp[12];
    outp[0] = constant_offset[st];
    outp[1] = linear_trend[st];

    #pragma unroll
    for (int i = 0; i < NSEAS; ++i) {
        float smA = OMS * seas_amp[st * NSEAS + i] + S * accA[i];
        float sp, cp;
        sincosf(seas_phase[st * NSEAS + i], &sp, &cp);
        float re = OMS * cp + S * accRe[i];
        float im = OMS * sp + S * accIm[i];
        // cos(atan2(im,re)) = re/r ; sin(atan2(im,re)) = im/r
        float r   = sqrtf(re * re + im * im);
        float inv = smA / fmaxf(r, 1e-30f);
        outp[2 + 2 * i] = re * inv;
        outp[3 + 2 * i] = im * inv;
    }

    #pragma unroll
    for (int i = 0; i < NRES; ++i) {
        float a = res_amp[st * NRES + i];
        float sp, cp;
        sincosf(res_phase[st * NRES + i], &sp, &cp);
        outp[2 + 2 * (NSEAS + i)] = a * cp;
        outp[3 + 2 * (NSEAS + i)] = a * sp;
    }

    f32x4* po = reinterpret_cast<f32x4*>(params + (size_t)st * 12);
    po[0] = f32x4{outp[0], outp[1], outp[2],  outp[3]};
    po[1] = f32x4{outp[4], outp[5], outp[6],  outp[7]};
    po[2] = f32x4{outp[8], outp[9], outp[10], outp[11]};
}

// Kernel B: stream the [N x T] output. Write-roofline target.
// Per block: stage SPB stations' 12 coeffs in LDS; each thread owns 4
// consecutive t, time-basis tables live in registers (loaded, not computed).
__global__ __launch_bounds__(BSIG, 6) void signals_kernel(
    const float* __restrict__ time_vector,
    const float* __restrict__ params,
    const float* __restrict__ sinT,
    const float* __restrict__ cosT,
    float* __restrict__ out,
    int N, int T, int spb)
{
    __shared__ float sp[SPB * 12];

    int tid   = threadIdx.x;
    int stBeg = blockIdx.x * spb;
    int stEnd = min(stBeg + spb, N);
    int nst   = stEnd - stBeg;
    if (nst <= 0) return;  // whole block idle (no barrier executed)

    // Cooperative coalesced load of this block's params into LDS.
    int nf4 = nst * 3;  // nst*12/4 float4s
    {
        const f32x4* src = reinterpret_cast<const f32x4*>(params + (size_t)stBeg * 12);
        f32x4* dst = reinterpret_cast<f32x4*>(sp);
        for (int i = tid; i < nf4; i += BSIG) dst[i] = src[i];
    }
    __syncthreads();

    int t0 = tid * 4;
    bool active = (t0 + 3) < T;

    float tv[4];
    float sT[NCOMP][4], cT[NCOMP][4];
    if (active) {
        f32x4 t4 = *reinterpret_cast<const f32x4*>(time_vector + t0);
        tv[0] = t4.x; tv[1] = t4.y; tv[2] = t4.z; tv[3] = t4.w;
        #pragma unroll
        for (int c = 0; c < NCOMP; ++c) {
            f32x4 s4 = *reinterpret_cast<const f32x4*>(sinT + c * T + t0);
            f32x4 c4 = *reinterpret_cast<const f32x4*>(cosT + c * T + t0);
            sT[c][0] = s4.x; sT[c][1] = s4.y; sT[c][2] = s4.z; sT[c][3] = s4.w;
            cT[c][0] = c4.x; cT[c][1] = c4.y; cT[c][2] = c4.z; cT[c][3] = c4.w;
        }
    }

    float* orow = out + (size_t)stBeg * T + t0;

    for (int st = 0; st < nst; ++st, orow += T) {
        const f32x4* pv = reinterpret_cast<const f32x4*>(sp + st * 12);
        f32x4 P0 = pv[0], P1 = pv[1], P2 = pv[2];
        float off = P0.x, trend = P0.y;
        float cs[NCOMP], cc[NCOMP];
        cs[0] = P0.z; cc[0] = P0.w;
        cs[1] = P1.x; cc[1] = P1.y;
        cs[2] = P1.z; cc[2] = P1.w;
        cs[3] = P2.x; cc[3] = P2.y;
        cs[4] = P2.z; cc[4] = P2.w;

        if (active) {
            float v[4];
            #pragma unroll
            for (int j = 0; j < 4; ++j) {
                float acc = fmaf(trend, tv[j], off);
                #pragma unroll
                for (int i = 0; i < NCOMP; ++i) {
                    acc = fmaf(cs[i], sT[i][j], acc);
                    acc = fmaf(cc[i], cT[i][j], acc);
                }
                v[j] = acc;
            }
            f32x4 o = {v[0], v[1], v[2], v[3]};
            __builtin_nontemporal_store(o, reinterpret_cast<f32x4*>(orow));
        } else if (t0 < T) {
            // generic tail (unused for T=1000) — scalar path
            for (int j = 0; j < 4 && t0 + j < T; ++j) {
                int t = t0 + j;
                float acc = fmaf(trend, time_vector[t], off);
                for (int i = 0; i < NCOMP; ++i) {
                    acc = fmaf(cs[i], sinT[i * T + t], acc);
                    acc = fmaf(cc[i], cosT[i * T + t], acc);
                }
                orow[j] = acc;
            }
        }
    }
}

extern "C" void kernel_launch(void* const* d_in, const int* in_sizes, int n_in,
                              void* d_out, int out_size, void* d_ws, size_t ws_size,
                              hipStream_t stream) {
    const float* time_vector     = (const float*)d_in[0];
    const float* constant_offset = (const float*)d_in[1];
    const float* linear_trend    = (const float*)d_in[2];
    const float* seas_amp        = (const float*)d_in[3];
    const float* seas_phase      = (const float*)d_in[4];
    const float* res_amp         = (const float*)d_in[5];
    const float* res_phase       = (const float*)d_in[6];
    const float* res_periods     = (const float*)d_in[7];
    const float* periods         = (const float*)d_in[8];
    const int*   nb_idx          = (const int*)d_in[9];
    const float* nb_w            = (const float*)d_in[10];

    int T = in_sizes[0];
    int N = in_sizes[1];

    float* params = (float*)d_ws;              // N*12 floats
    float* sinT   = params + (size_t)N * 12;   // 5*T
    float* cosT   = sinT + (size_t)NCOMP * T;  // 5*T
    float* out    = (float*)d_out;

    // Time-basis tables (independent of smoothing).
    {
        int threads = 256;
        int blocks  = (T + threads - 1) / threads;
        build_tables_kernel<<<blocks, threads, 0, stream>>>(
            time_vector, periods, res_periods, sinT, cosT, T);
    }

    // Per-station smoothed coefficients.
    {
        int threads = 256;
        int blocks  = (N + threads - 1) / threads;
        smooth_params_kernel<<<blocks, threads, 0, stream>>>(
            constant_offset, linear_trend, seas_amp, seas_phase,
            res_amp, res_phase, nb_idx, nb_w, params, N);
    }

    // Stream the output.
    {
        int spb  = SPB;
        int grid = (N + spb - 1) / spb;
        signals_kernel<<<grid, BSIG, 0, stream>>>(
            time_vector, params, sinT, cosT, out, N, T, spb);
    }
}

// Round 3
// 111.517 us; speedup vs baseline: 1.3990x; 1.3990x over previous
//
#include <hip/hip_runtime.h>

typedef float f32x4 __attribute__((ext_vector_type(4)));

#define NSEAS 3
#define NRES  2
#define NCOMP 5
#define KNB   8
#define TWO_PI_F 6.28318530717958647692f
#define SPB 48           // stations per signals-block (multiple of 4)
#define BSIG 256         // signals block size

// ---------------------------------------------------------------------------
// ws layout (floats): [0, N*12)            params
//                     [N*12, N*12+5T)      sinT[comp][t]
//                     [N*12+5T, N*12+10T)  cosT[comp][t]
// ---------------------------------------------------------------------------

// Tiny kernel: sin/cos(2*pi*f_c*t) tables, 5 components x T.
__global__ void build_tables_kernel(
    const float* __restrict__ time_vector,
    const float* __restrict__ periods,
    const float* __restrict__ res_periods,
    float* __restrict__ sinT,
    float* __restrict__ cosT,
    int T)
{
    int t = blockIdx.x * blockDim.x + threadIdx.x;
    if (t >= T) return;
    float tt = time_vector[t];
    #pragma unroll
    for (int c = 0; c < NCOMP; ++c) {
        float f = (c < NSEAS) ? (1.0f / periods[c])
                              : (1.0f / res_periods[c - NSEAS]);
        float s, co;
        __sincosf(TWO_PI_F * f * tt, &s, &co);
        sinT[c * T + t] = s;
        cosT[c * T + t] = co;
    }
}

// Kernel A: spatial smoothing -> 12 coefficients per station.
// params[st*12 + 0] = offset, +1 = trend,
// +2+2i = A_i*cos(phi_i) (sin-basis coeff), +3+2i = A_i*sin(phi_i) (cos-basis)
__global__ void smooth_params_kernel(
    const float* __restrict__ constant_offset,
    const float* __restrict__ linear_trend,
    const float* __restrict__ seas_amp,
    const float* __restrict__ seas_phase,
    const float* __restrict__ res_amp,
    const float* __restrict__ res_phase,
    const int*   __restrict__ nb_idx,
    const float* __restrict__ nb_w,
    float* __restrict__ params,
    int N)
{
    int st = blockIdx.x * blockDim.x + threadIdx.x;
    if (st >= N) return;

    const float S = 0.12f, OMS = 1.0f - 0.12f;

    const int4*  ip = reinterpret_cast<const int4*>(nb_idx + st * KNB);
    const f32x4* wp = reinterpret_cast<const f32x4*>(nb_w + st * KNB);
    int4  i0 = ip[0], i1 = ip[1];
    f32x4 w0 = wp[0], w1 = wp[1];
    int   idx[KNB] = {i0.x, i0.y, i0.z, i0.w, i1.x, i1.y, i1.z, i1.w};
    float w[KNB]   = {w0.x, w0.y, w0.z, w0.w, w1.x, w1.y, w1.z, w1.w};

    float accA[NSEAS]  = {0.f, 0.f, 0.f};
    float accRe[NSEAS] = {0.f, 0.f, 0.f};
    float accIm[NSEAS] = {0.f, 0.f, 0.f};

    #pragma unroll
    for (int k = 0; k < KNB; ++k) {
        int nb = idx[k];
        #pragma unroll
        for (int i = 0; i < NSEAS; ++i) {
            float a = seas_amp[nb * NSEAS + i];
            float p = seas_phase[nb * NSEAS + i];
            float sp, cp;
            __sincosf(p, &sp, &cp);
            accA[i]  = fmaf(w[k], a,  accA[i]);
            accRe[i] = fmaf(w[k], cp, accRe[i]);
            accIm[i] = fmaf(w[k], sp, accIm[i]);
        }
    }

    float outp[12];
    outp[0] = constant_offset[st];
    outp[1] = linear_trend[st];

    #pragma unroll
    for (int i = 0; i < NSEAS; ++i) {
        float smA = OMS * seas_amp[st * NSEAS + i] + S * accA[i];
        float sp, cp;
        __sincosf(seas_phase[st * NSEAS + i], &sp, &cp);
        float re = OMS * cp + S * accRe[i];
        float im = OMS * sp + S * accIm[i];
        // cos(atan2(im,re)) = re/r ; sin(atan2(im,re)) = im/r
        float r   = sqrtf(re * re + im * im);
        float inv = smA / fmaxf(r, 1e-30f);
        outp[2 + 2 * i] = re * inv;
        outp[3 + 2 * i] = im * inv;
    }

    #pragma unroll
    for (int i = 0; i < NRES; ++i) {
        float a = res_amp[st * NRES + i];
        float sp, cp;
        __sincosf(res_phase[st * NRES + i], &sp, &cp);
        outp[2 + 2 * (NSEAS + i)] = a * cp;
        outp[3 + 2 * (NSEAS + i)] = a * sp;
    }

    f32x4* po = reinterpret_cast<f32x4*>(params + (size_t)st * 12);
    po[0] = f32x4{outp[0], outp[1], outp[2],  outp[3]};
    po[1] = f32x4{outp[4], outp[5], outp[6],  outp[7]};
    po[2] = f32x4{outp[8], outp[9], outp[10], outp[11]};
}

// Kernel B: stream the [N x T] output, write-roofline target.
// Thread owns 4 consecutive t; time-basis tables in registers (loaded);
// station loop unrolled x4 so 4 param-load + 4 store streams are in flight.
__global__ __launch_bounds__(BSIG) void signals_kernel(
    const float* __restrict__ time_vector,
    const float* __restrict__ params,
    const float* __restrict__ sinT,
    const float* __restrict__ cosT,
    float* __restrict__ out,
    int N, int T, int spb)
{
    int tid = threadIdx.x;
    int t0  = tid * 4;
    bool active = (t0 + 3) < T;   // T=1000 -> tids 0..249

    float tv[4];
    float sT[NCOMP][4], cT[NCOMP][4];
    if (active) {
        f32x4 t4 = *reinterpret_cast<const f32x4*>(time_vector + t0);
        tv[0] = t4.x; tv[1] = t4.y; tv[2] = t4.z; tv[3] = t4.w;
        #pragma unroll
        for (int c = 0; c < NCOMP; ++c) {
            f32x4 s4 = *reinterpret_cast<const f32x4*>(sinT + c * T + t0);
            f32x4 c4 = *reinterpret_cast<const f32x4*>(cosT + c * T + t0);
            sT[c][0] = s4.x; sT[c][1] = s4.y; sT[c][2] = s4.z; sT[c][3] = s4.w;
            cT[c][0] = c4.x; cT[c][1] = c4.y; cT[c][2] = c4.z; cT[c][3] = c4.w;
        }
    }

    int stBeg = blockIdx.x * spb;
    int stEnd = min(stBeg + spb, N);
    int st = stBeg;

    // Main: 4 stations per iteration (independent load/compute/store chains).
    for (; st + 4 <= stEnd; st += 4) {
        float off[4], trend[4], cs[4][NCOMP], cc[4][NCOMP];
        #pragma unroll
        for (int u = 0; u < 4; ++u) {
            const f32x4* p = reinterpret_cast<const f32x4*>(params + (size_t)(st + u) * 12);
            f32x4 P0 = p[0], P1 = p[1], P2 = p[2];
            off[u] = P0.x; trend[u] = P0.y;
            cs[u][0] = P0.z; cc[u][0] = P0.w;
            cs[u][1] = P1.x; cc[u][1] = P1.y;
            cs[u][2] = P1.z; cc[u][2] = P1.w;
            cs[u][3] = P2.x; cc[u][3] = P2.y;
            cs[u][4] = P2.z; cc[u][4] = P2.w;
        }
        if (active) {
            #pragma unroll
            for (int u = 0; u < 4; ++u) {
                float v[4];
                #pragma unroll
                for (int j = 0; j < 4; ++j) {
                    float acc = fmaf(trend[u], tv[j], off[u]);
                    #pragma unroll
                    for (int i = 0; i < NCOMP; ++i) {
                        acc = fmaf(cs[u][i], sT[i][j], acc);
                        acc = fmaf(cc[u][i], cT[i][j], acc);
                    }
                    v[j] = acc;
                }
                f32x4 o = {v[0], v[1], v[2], v[3]};
                *reinterpret_cast<f32x4*>(out + (size_t)(st + u) * T + t0) = o;
            }
        }
    }

    // Remainder stations.
    for (; st < stEnd; ++st) {
        const f32x4* p = reinterpret_cast<const f32x4*>(params + (size_t)st * 12);
        f32x4 P0 = p[0], P1 = p[1], P2 = p[2];
        float off = P0.x, trend = P0.y;
        float cs[NCOMP], cc[NCOMP];
        cs[0] = P0.z; cc[0] = P0.w;
        cs[1] = P1.x; cc[1] = P1.y;
        cs[2] = P1.z; cc[2] = P1.w;
        cs[3] = P2.x; cc[3] = P2.y;
        cs[4] = P2.z; cc[4] = P2.w;
        if (active) {
            float v[4];
            #pragma unroll
            for (int j = 0; j < 4; ++j) {
                float acc = fmaf(trend, tv[j], off);
                #pragma unroll
                for (int i = 0; i < NCOMP; ++i) {
                    acc = fmaf(cs[i], sT[i][j], acc);
                    acc = fmaf(cc[i], cT[i][j], acc);
                }
                v[j] = acc;
            }
            f32x4 o = {v[0], v[1], v[2], v[3]};
            *reinterpret_cast<f32x4*>(out + (size_t)st * T + t0) = o;
        } else if (t0 < T) {
            for (int j = 0; j < 4 && t0 + j < T; ++j) {
                int t = t0 + j;
                float acc = fmaf(trend, time_vector[t], off);
                for (int i = 0; i < NCOMP; ++i) {
                    acc = fmaf(cs[i], sinT[i * T + t], acc);
                    acc = fmaf(cc[i], cosT[i * T + t], acc);
                }
                out[(size_t)st * T + t] = acc;
            }
        }
    }
}

extern "C" void kernel_launch(void* const* d_in, const int* in_sizes, int n_in,
                              void* d_out, int out_size, void* d_ws, size_t ws_size,
                              hipStream_t stream) {
    const float* time_vector     = (const float*)d_in[0];
    const float* constant_offset = (const float*)d_in[1];
    const float* linear_trend    = (const float*)d_in[2];
    const float* seas_amp        = (const float*)d_in[3];
    const float* seas_phase      = (const float*)d_in[4];
    const float* res_amp         = (const float*)d_in[5];
    const float* res_phase       = (const float*)d_in[6];
    const float* res_periods     = (const float*)d_in[7];
    const float* periods         = (const float*)d_in[8];
    const int*   nb_idx          = (const int*)d_in[9];
    const float* nb_w            = (const float*)d_in[10];

    int T = in_sizes[0];
    int N = in_sizes[1];

    float* params = (float*)d_ws;              // N*12 floats
    float* sinT   = params + (size_t)N * 12;   // 5*T
    float* cosT   = sinT + (size_t)NCOMP * T;  // 5*T
    float* out    = (float*)d_out;

    // Time-basis tables.
    {
        int threads = 256;
        int blocks  = (T + threads - 1) / threads;
        build_tables_kernel<<<blocks, threads, 0, stream>>>(
            time_vector, periods, res_periods, sinT, cosT, T);
    }

    // Per-station smoothed coefficients.
    {
        int threads = 256;
        int blocks  = (N + threads - 1) / threads;
        smooth_params_kernel<<<blocks, threads, 0, stream>>>(
            constant_offset, linear_trend, seas_amp, seas_phase,
            res_amp, res_phase, nb_idx, nb_w, params, N);
    }

    // Stream the output.
    {
        int spb  = SPB;
        int grid = (N + spb - 1) / spb;
        signals_kernel<<<grid, BSIG, 0, stream>>>(
            time_vector, params, sinT, cosT, out, N, T, spb);
    }
}

// Round 4
// 97.279 us; speedup vs baseline: 1.6037x; 1.1464x over previous
//
#include <hip/hip_runtime.h>

typedef float f32x4 __attribute__((ext_vector_type(4)));

#define NSEAS 3
#define NRES  2
#define NCOMP 5
#define KNB   8
#define TWO_PI_F 6.28318530717958647692f
#define SPB  50          // stations per block; 2000 * 50 = 100000 exactly
#define BSIG 256         // block size

// Single fused kernel.
// Phase 1a: lanes tid==5*s (s<SPB, spread across all 4 waves) compute the
//           spatially-smoothed 12 coefficients for station stBeg+s -> LDS.
// Phase 1b: every streaming-active thread computes its sin/cos time basis
//           (5 components x 4 t-values) in registers via __sincosf.
// Phase 2:  barrier, then stream 50 rows x T f32 with x4-unrolled station
//           loop; coeffs via broadcast ds_read_b128.
__global__ __launch_bounds__(BSIG) void fused_insar_kernel(
    const float* __restrict__ time_vector,
    const float* __restrict__ constant_offset,
    const float* __restrict__ linear_trend,
    const float* __restrict__ seas_amp,
    const float* __restrict__ seas_phase,
    const float* __restrict__ res_amp,
    const float* __restrict__ res_phase,
    const float* __restrict__ res_periods,
    const float* __restrict__ periods,
    const int*   __restrict__ nb_idx,
    const float* __restrict__ nb_w,
    float* __restrict__ out,
    int N, int T)
{
    __shared__ __align__(16) float sp[SPB * 12];

    const int tid   = threadIdx.x;
    const int stBeg = blockIdx.x * SPB;
    const int nst   = min(SPB, N - stBeg);   // 50 for all blocks here

    // ---------------- Phase 1a: smoothing -> LDS ----------------
    {
        int s = tid / 5;
        if (tid == s * 5 && s < nst) {
            int st = stBeg + s;
            const float S = 0.12f, OMS = 1.0f - 0.12f;

            const int4*  ip = reinterpret_cast<const int4*>(nb_idx + st * KNB);
            const f32x4* wp = reinterpret_cast<const f32x4*>(nb_w + st * KNB);
            int4  i0 = ip[0], i1 = ip[1];
            f32x4 w0 = wp[0], w1 = wp[1];
            int   idx[KNB] = {i0.x, i0.y, i0.z, i0.w, i1.x, i1.y, i1.z, i1.w};
            float w[KNB]   = {w0.x, w0.y, w0.z, w0.w, w1.x, w1.y, w1.z, w1.w};

            float accA[NSEAS]  = {0.f, 0.f, 0.f};
            float accRe[NSEAS] = {0.f, 0.f, 0.f};
            float accIm[NSEAS] = {0.f, 0.f, 0.f};

            #pragma unroll
            for (int k = 0; k < KNB; ++k) {
                int nb = idx[k];
                #pragma unroll
                for (int i = 0; i < NSEAS; ++i) {
                    float a = seas_amp[nb * NSEAS + i];
                    float p = seas_phase[nb * NSEAS + i];
                    float spn, cpn;
                    __sincosf(p, &spn, &cpn);
                    accA[i]  = fmaf(w[k], a,   accA[i]);
                    accRe[i] = fmaf(w[k], cpn, accRe[i]);
                    accIm[i] = fmaf(w[k], spn, accIm[i]);
                }
            }

            float outp[12];
            outp[0] = constant_offset[st];
            outp[1] = linear_trend[st];

            #pragma unroll
            for (int i = 0; i < NSEAS; ++i) {
                float smA = OMS * seas_amp[st * NSEAS + i] + S * accA[i];
                float spn, cpn;
                __sincosf(seas_phase[st * NSEAS + i], &spn, &cpn);
                float re = OMS * cpn + S * accRe[i];
                float im = OMS * spn + S * accIm[i];
                // cos(atan2(im,re)) = re/r ; sin(atan2(im,re)) = im/r
                float r   = sqrtf(re * re + im * im);
                float inv = smA / fmaxf(r, 1e-30f);
                outp[2 + 2 * i] = re * inv;
                outp[3 + 2 * i] = im * inv;
            }

            #pragma unroll
            for (int i = 0; i < NRES; ++i) {
                float a = res_amp[st * NRES + i];
                float spn, cpn;
                __sincosf(res_phase[st * NRES + i], &spn, &cpn);
                outp[2 + 2 * (NSEAS + i)] = a * cpn;
                outp[3 + 2 * (NSEAS + i)] = a * spn;
            }

            f32x4* po = reinterpret_cast<f32x4*>(sp + s * 12);
            po[0] = f32x4{outp[0], outp[1], outp[2],  outp[3]};
            po[1] = f32x4{outp[4], outp[5], outp[6],  outp[7]};
            po[2] = f32x4{outp[8], outp[9], outp[10], outp[11]};
        }
    }

    // ---------------- Phase 1b: time basis in registers ----------------
    const int t0 = tid * 4;
    const bool active = (t0 + 3) < T;

    float tv[4];
    float sT[NCOMP][4], cT[NCOMP][4];
    if (active) {
        f32x4 t4 = *reinterpret_cast<const f32x4*>(time_vector + t0);
        tv[0] = t4.x; tv[1] = t4.y; tv[2] = t4.z; tv[3] = t4.w;
        #pragma unroll
        for (int c = 0; c < NCOMP; ++c) {
            float f = (c < NSEAS) ? (1.0f / periods[c])
                                  : (1.0f / res_periods[c - NSEAS]);
            float wc = TWO_PI_F * f;
            #pragma unroll
            for (int j = 0; j < 4; ++j) {
                __sincosf(wc * tv[j], &sT[c][j], &cT[c][j]);
            }
        }
    }

    __syncthreads();

    // ---------------- Phase 2: stream the output ----------------
    int s = 0;

    // x4-unrolled main loop: 4 independent load/compute/store chains.
    for (; s + 4 <= nst; s += 4) {
        float off[4], trend[4], cs[4][NCOMP], cc[4][NCOMP];
        #pragma unroll
        for (int u = 0; u < 4; ++u) {
            const f32x4* pv = reinterpret_cast<const f32x4*>(sp + (s + u) * 12);
            f32x4 P0 = pv[0], P1 = pv[1], P2 = pv[2];
            off[u] = P0.x; trend[u] = P0.y;
            cs[u][0] = P0.z; cc[u][0] = P0.w;
            cs[u][1] = P1.x; cc[u][1] = P1.y;
            cs[u][2] = P1.z; cc[u][2] = P1.w;
            cs[u][3] = P2.x; cc[u][3] = P2.y;
            cs[u][4] = P2.z; cc[u][4] = P2.w;
        }
        if (active) {
            #pragma unroll
            for (int u = 0; u < 4; ++u) {
                float v[4];
                #pragma unroll
                for (int j = 0; j < 4; ++j) {
                    float acc = fmaf(trend[u], tv[j], off[u]);
                    #pragma unroll
                    for (int i = 0; i < NCOMP; ++i) {
                        acc = fmaf(cs[u][i], sT[i][j], acc);
                        acc = fmaf(cc[u][i], cT[i][j], acc);
                    }
                    v[j] = acc;
                }
                f32x4 o = {v[0], v[1], v[2], v[3]};
                *reinterpret_cast<f32x4*>(out + (size_t)(stBeg + s + u) * T + t0) = o;
            }
        }
    }

    // Remainder stations (nst % 4).
    for (; s < nst; ++s) {
        const f32x4* pv = reinterpret_cast<const f32x4*>(sp + s * 12);
        f32x4 P0 = pv[0], P1 = pv[1], P2 = pv[2];
        float off = P0.x, trend = P0.y;
        float cs[NCOMP], cc[NCOMP];
        cs[0] = P0.z; cc[0] = P0.w;
        cs[1] = P1.x; cc[1] = P1.y;
        cs[2] = P1.z; cc[2] = P1.w;
        cs[3] = P2.x; cc[3] = P2.y;
        cs[4] = P2.z; cc[4] = P2.w;

        if (active) {
            float v[4];
            #pragma unroll
            for (int j = 0; j < 4; ++j) {
                float acc = fmaf(trend, tv[j], off);
                #pragma unroll
                for (int i = 0; i < NCOMP; ++i) {
                    acc = fmaf(cs[i], sT[i][j], acc);
                    acc = fmaf(cc[i], cT[i][j], acc);
                }
                v[j] = acc;
            }
            f32x4 o = {v[0], v[1], v[2], v[3]};
            *reinterpret_cast<f32x4*>(out + (size_t)(stBeg + s) * T + t0) = o;
        } else if (t0 < T) {
            // Generic T-tail (unused for T=1000): compute directly.
            for (int j = 0; j < 4 && t0 + j < T; ++j) {
                int t = t0 + j;
                float tt = time_vector[t];
                float acc = fmaf(trend, tt, off);
                for (int i = 0; i < NCOMP; ++i) {
                    float f = (i < NSEAS) ? (1.0f / periods[i])
                                          : (1.0f / res_periods[i - NSEAS]);
                    float sv, cv;
                    __sincosf(TWO_PI_F * f * tt, &sv, &cv);
                    acc = fmaf(cs[i], sv, acc);
                    acc = fmaf(cc[i], cv, acc);
                }
                out[(size_t)(stBeg + s) * T + t] = acc;
            }
        }
    }
}

extern "C" void kernel_launch(void* const* d_in, const int* in_sizes, int n_in,
                              void* d_out, int out_size, void* d_ws, size_t ws_size,
                              hipStream_t stream) {
    const float* time_vector     = (const float*)d_in[0];
    const float* constant_offset = (const float*)d_in[1];
    const float* linear_trend    = (const float*)d_in[2];
    const float* seas_amp        = (const float*)d_in[3];
    const float* seas_phase     = (const float*)d_in[4];
    const float* res_amp         = (const float*)d_in[5];
    const float* res_phase       = (const float*)d_in[6];
    const float* res_periods     = (const float*)d_in[7];
    const float* periods         = (const float*)d_in[8];
    const int*   nb_idx          = (const int*)d_in[9];
    const float* nb_w            = (const float*)d_in[10];

    int T = in_sizes[0];
    int N = in_sizes[1];

    float* out = (float*)d_out;

    int grid = (N + SPB - 1) / SPB;   // 2000 blocks for N=100000
    fused_insar_kernel<<<grid, BSIG, 0, stream>>>(
        time_vector, constant_offset, linear_trend,
        seas_amp, seas_phase, res_amp, res_phase,
        res_periods, periods, nb_idx, nb_w,
        out, N, T);
}

// Round 5
// 96.034 us; speedup vs baseline: 1.6245x; 1.0130x over previous
//
#include <hip/hip_runtime.h>

typedef float f32x4 __attribute__((ext_vector_type(4)));
typedef float f32x2 __attribute__((ext_vector_type(2)));

#define NSEAS 3
#define NRES  2
#define NCOMP 5
#define KNB   8
#define TWO_PI_F 6.28318530717958647692f
#define SPB  100         // stations per block; 1000 * 100 = 100000 exactly
#define BSIG 256         // block size

static __device__ __forceinline__ f32x2 bc2(float x) {
    f32x2 r; r.x = x; r.y = x; return r;
}

// Single fused kernel.
// Phase 1a: lane tid<nst computes smoothed 12 coeffs for station stBeg+tid -> LDS.
// Phase 1b: each streaming thread builds its sin/cos time basis in registers.
// Phase 2:  software-pipelined (ping-pong) x4-station groups; packed f32 FMAs;
//           coeff ds_read_b128 for group g+1 issued before group g's FMA block.
__global__ __launch_bounds__(BSIG) void fused_insar_kernel(
    const float* __restrict__ time_vector,
    const float* __restrict__ constant_offset,
    const float* __restrict__ linear_trend,
    const float* __restrict__ seas_amp,
    const float* __restrict__ seas_phase,
    const float* __restrict__ res_amp,
    const float* __restrict__ res_phase,
    const float* __restrict__ res_periods,
    const float* __restrict__ periods,
    const int*   __restrict__ nb_idx,
    const float* __restrict__ nb_w,
    float* __restrict__ out,
    int N, int T)
{
    __shared__ __align__(16) float sp[SPB * 12];

    const int tid   = threadIdx.x;
    const int stBeg = blockIdx.x * SPB;
    const int nst   = min(SPB, N - stBeg);   // 100 for all blocks here

    // ---------------- Phase 1a: smoothing -> LDS (one lane per station) ---
    if (tid < nst) {
        const int st = stBeg + tid;
        const float S = 0.12f, OMS = 1.0f - 0.12f;

        const int4*  ip = reinterpret_cast<const int4*>(nb_idx + st * KNB);
        const f32x4* wp = reinterpret_cast<const f32x4*>(nb_w + st * KNB);
        int4  i0 = ip[0], i1 = ip[1];
        f32x4 w0 = wp[0], w1 = wp[1];
        int   idx[KNB] = {i0.x, i0.y, i0.z, i0.w, i1.x, i1.y, i1.z, i1.w};
        float w[KNB]   = {w0.x, w0.y, w0.z, w0.w, w1.x, w1.y, w1.z, w1.w};

        float accA[NSEAS]  = {0.f, 0.f, 0.f};
        float accRe[NSEAS] = {0.f, 0.f, 0.f};
        float accIm[NSEAS] = {0.f, 0.f, 0.f};

        #pragma unroll
        for (int k = 0; k < KNB; ++k) {
            int nb = idx[k];
            #pragma unroll
            for (int i = 0; i < NSEAS; ++i) {
                float a = seas_amp[nb * NSEAS + i];
                float p = seas_phase[nb * NSEAS + i];
                float spn, cpn;
                __sincosf(p, &spn, &cpn);
                accA[i]  = fmaf(w[k], a,   accA[i]);
                accRe[i] = fmaf(w[k], cpn, accRe[i]);
                accIm[i] = fmaf(w[k], spn, accIm[i]);
            }
        }

        float outp[12];
        outp[0] = constant_offset[st];
        outp[1] = linear_trend[st];

        #pragma unroll
        for (int i = 0; i < NSEAS; ++i) {
            float smA = OMS * seas_amp[st * NSEAS + i] + S * accA[i];
            float spn, cpn;
            __sincosf(seas_phase[st * NSEAS + i], &spn, &cpn);
            float re = OMS * cpn + S * accRe[i];
            float im = OMS * spn + S * accIm[i];
            // cos(atan2(im,re)) = re/r ; sin(atan2(im,re)) = im/r
            float r   = sqrtf(re * re + im * im);
            float inv = smA / fmaxf(r, 1e-30f);
            outp[2 + 2 * i] = re * inv;
            outp[3 + 2 * i] = im * inv;
        }

        #pragma unroll
        for (int i = 0; i < NRES; ++i) {
            float a = res_amp[st * NRES + i];
            float spn, cpn;
            __sincosf(res_phase[st * NRES + i], &spn, &cpn);
            outp[2 + 2 * (NSEAS + i)] = a * cpn;
            outp[3 + 2 * (NSEAS + i)] = a * spn;
        }

        f32x4* po = reinterpret_cast<f32x4*>(sp + tid * 12);
        po[0] = f32x4{outp[0], outp[1], outp[2],  outp[3]};
        po[1] = f32x4{outp[4], outp[5], outp[6],  outp[7]};
        po[2] = f32x4{outp[8], outp[9], outp[10], outp[11]};
    }

    // ---------------- Phase 1b: time basis in registers ----------------
    const int t0 = tid * 4;
    const bool active = (t0 + 3) < T;

    f32x2 tv2[2];
    f32x2 sT2[NCOMP][2], cT2[NCOMP][2];
    if (active) {
        f32x4 t4 = *reinterpret_cast<const f32x4*>(time_vector + t0);
        tv2[0].x = t4.x; tv2[0].y = t4.y;
        tv2[1].x = t4.z; tv2[1].y = t4.w;
        #pragma unroll
        for (int c = 0; c < NCOMP; ++c) {
            float f = (c < NSEAS) ? (1.0f / periods[c])
                                  : (1.0f / res_periods[c - NSEAS]);
            float wc = TWO_PI_F * f;
            float s0, c0, s1, c1, s2, c2, s3, c3;
            __sincosf(wc * t4.x, &s0, &c0);
            __sincosf(wc * t4.y, &s1, &c1);
            __sincosf(wc * t4.z, &s2, &c2);
            __sincosf(wc * t4.w, &s3, &c3);
            sT2[c][0].x = s0; sT2[c][0].y = s1;
            sT2[c][1].x = s2; sT2[c][1].y = s3;
            cT2[c][0].x = c0; cT2[c][0].y = c1;
            cT2[c][1].x = c2; cT2[c][1].y = c3;
        }
    }

    __syncthreads();

    // ---------------- Phase 2: pipelined streaming ----------------
    const int ngr = nst / 4;   // full 4-station groups (25 here)

    // Load the 12 coeff-vectors (4 stations x 3 f32x4) of group g.
    auto ldg = [&](int g, f32x4* C) {
        const f32x4* base = reinterpret_cast<const f32x4*>(sp) + g * 12;
        #pragma unroll
        for (int i = 0; i < 12; ++i) C[i] = base[i];
    };

    // Compute + store group g from coeff regs.
    auto docg = [&](int g, const f32x4* C) {
        if (!active) return;
        #pragma unroll
        for (int u = 0; u < 4; ++u) {
            f32x4 P0 = C[3 * u], P1 = C[3 * u + 1], P2 = C[3 * u + 2];
            f32x2 of = bc2(P0.x), tr = bc2(P0.y);
            f32x2 a0 = __builtin_elementwise_fma(tr, tv2[0], of);
            f32x2 a1 = __builtin_elementwise_fma(tr, tv2[1], of);
            a0 = __builtin_elementwise_fma(bc2(P0.z), sT2[0][0], a0);
            a1 = __builtin_elementwise_fma(bc2(P0.z), sT2[0][1], a1);
            a0 = __builtin_elementwise_fma(bc2(P0.w), cT2[0][0], a0);
            a1 = __builtin_elementwise_fma(bc2(P0.w), cT2[0][1], a1);
            a0 = __builtin_elementwise_fma(bc2(P1.x), sT2[1][0], a0);
            a1 = __builtin_elementwise_fma(bc2(P1.x), sT2[1][1], a1);
            a0 = __builtin_elementwise_fma(bc2(P1.y), cT2[1][0], a0);
            a1 = __builtin_elementwise_fma(bc2(P1.y), cT2[1][1], a1);
            a0 = __builtin_elementwise_fma(bc2(P1.z), sT2[2][0], a0);
            a1 = __builtin_elementwise_fma(bc2(P1.z), sT2[2][1], a1);
            a0 = __builtin_elementwise_fma(bc2(P1.w), cT2[2][0], a0);
            a1 = __builtin_elementwise_fma(bc2(P1.w), cT2[2][1], a1);
            a0 = __builtin_elementwise_fma(bc2(P2.x), sT2[3][0], a0);
            a1 = __builtin_elementwise_fma(bc2(P2.x), sT2[3][1], a1);
            a0 = __builtin_elementwise_fma(bc2(P2.y), cT2[3][0], a0);
            a1 = __builtin_elementwise_fma(bc2(P2.y), cT2[3][1], a1);
            a0 = __builtin_elementwise_fma(bc2(P2.z), sT2[4][0], a0);
            a1 = __builtin_elementwise_fma(bc2(P2.z), sT2[4][1], a1);
            a0 = __builtin_elementwise_fma(bc2(P2.w), cT2[4][0], a0);
            a1 = __builtin_elementwise_fma(bc2(P2.w), cT2[4][1], a1);
            f32x4 o; o.x = a0.x; o.y = a0.y; o.z = a1.x; o.w = a1.y;
            *reinterpret_cast<f32x4*>(out + (size_t)(stBeg + 4 * g + u) * T + t0) = o;
        }
    };

    f32x4 A[12], B[12];
    if (ngr > 0) ldg(0, A);
    int g = 0;
    for (; g + 2 <= ngr; g += 2) {
        ldg(g + 1, B);           // issue next group's LDS reads early
        docg(g, A);              // FMAs hide the LDS latency
        if (g + 2 < ngr) ldg(g + 2, A);
        docg(g + 1, B);
    }
    if (g < ngr) docg(g, A);     // odd ngr: last group already in A

    // Remainder stations (nst % 4) — generic path.
    for (int s = ngr * 4; s < nst; ++s) {
        const f32x4* pv = reinterpret_cast<const f32x4*>(sp + s * 12);
        f32x4 P0 = pv[0], P1 = pv[1], P2 = pv[2];
        float off = P0.x, trend = P0.y;
        float cs[NCOMP] = {P0.z, P1.x, P1.z, P2.x, P2.z};
        float cc[NCOMP] = {P0.w, P1.y, P1.w, P2.y, P2.w};
        if (active) {
            float tvv[4] = {tv2[0].x, tv2[0].y, tv2[1].x, tv2[1].y};
            float v[4];
            #pragma unroll
            for (int j = 0; j < 4; ++j) {
                int p = j >> 1, l = j & 1;
                float acc = fmaf(trend, tvv[j], off);
                #pragma unroll
                for (int i = 0; i < NCOMP; ++i) {
                    float sv = l ? sT2[i][p].y : sT2[i][p].x;
                    float cv = l ? cT2[i][p].y : cT2[i][p].x;
                    acc = fmaf(cs[i], sv, acc);
                    acc = fmaf(cc[i], cv, acc);
                }
                v[j] = acc;
            }
            f32x4 o = {v[0], v[1], v[2], v[3]};
            *reinterpret_cast<f32x4*>(out + (size_t)(stBeg + s) * T + t0) = o;
        } else if (t0 < T) {
            for (int j = 0; j < 4 && t0 + j < T; ++j) {
                int t = t0 + j;
                float tt = time_vector[t];
                float acc = fmaf(trend, tt, off);
                for (int i = 0; i < NCOMP; ++i) {
                    float f = (i < NSEAS) ? (1.0f / periods[i])
                                          : (1.0f / res_periods[i - NSEAS]);
                    float sv, cv;
                    __sincosf(TWO_PI_F * f * tt, &sv, &cv);
                    acc = fmaf(cs[i], sv, acc);
                    acc = fmaf(cc[i], cv, acc);
                }
                out[(size_t)(stBeg + s) * T + t] = acc;
            }
        }
    }
}

extern "C" void kernel_launch(void* const* d_in, const int* in_sizes, int n_in,
                              void* d_out, int out_size, void* d_ws, size_t ws_size,
                              hipStream_t stream) {
    const float* time_vector     = (const float*)d_in[0];
    const float* constant_offset = (const float*)d_in[1];
    const float* linear_trend    = (const float*)d_in[2];
    const float* seas_amp        = (const float*)d_in[3];
    const float* seas_phase      = (const float*)d_in[4];
    const float* res_amp         = (const float*)d_in[5];
    const float* res_phase       = (const float*)d_in[6];
    const float* res_periods     = (const float*)d_in[7];
    const float* periods         = (const float*)d_in[8];
    const int*   nb_idx          = (const int*)d_in[9];
    const float* nb_w            = (const float*)d_in[10];

    int T = in_sizes[0];
    int N = in_sizes[1];

    float* out = (float*)d_out;

    int grid = (N + SPB - 1) / SPB;   // 1000 blocks for N=100000
    fused_insar_kernel<<<grid, BSIG, 0, stream>>>(
        time_vector, constant_offset, linear_trend,
        seas_amp, seas_phase, res_amp, res_phase,
        res_periods, periods, nb_idx, nb_w,
        out, N, T);
}